// Round 1
// baseline (982.525 us; speedup 1.0000x reference)
//
#include <hip/hip_runtime.h>
#include <hip/hip_bf16.h>

// MoE expert MLP: y[s] += sum_k topk_w[s,k] * silu(x[s] @ W1[e]^T) @ W2[e]^T
// Grouped-GEMM formulation: sort (s,k) pairs by expert, run per-expert tiled
// bf16 MFMA GEMMs (tolerance is 2% of absmax -> bf16 compute is fine).

#define SS 8192
#define HD 1024
#define FD 4096
#define NE 8
#define TK 2
#define NP (SS * TK)                 // 16384 token-expert pairs
#define MAX_TILES (NP / 128 + NE)    // 136 upper bound on 128-row tiles

typedef __bf16 bf16x8 __attribute__((ext_vector_type(8)));
typedef unsigned short us8 __attribute__((ext_vector_type(8)));
typedef float f32x4 __attribute__((ext_vector_type(4)));

static __device__ __forceinline__ unsigned short f2bf(float f) {
  union { float f; unsigned u; } v; v.f = f;
  unsigned r = (v.u + 0x7fffu + ((v.u >> 16) & 1u)) >> 16;  // RNE
  return (unsigned short)r;
}

static __device__ __forceinline__ bf16x8 frag_ld(const unsigned short* p) {
  union { us8 u; bf16x8 b; } v;
  v.u = *(const us8*)p;
  return v.b;
}

// ---------------- bucket building ----------------

__global__ void count_kernel(const int* __restrict__ topk_e, int* __restrict__ counts) {
  __shared__ int lc[NE];
  int tid = threadIdx.x;
  if (tid < NE) lc[tid] = 0;
  __syncthreads();
  int t = blockIdx.x * 256 + tid;
  atomicAdd(&lc[topk_e[t]], 1);
  __syncthreads();
  if (tid < NE) atomicAdd(&counts[tid], lc[tid]);
}

__global__ void plan_kernel(const int* __restrict__ counts, int* __restrict__ offsets,
                            int* __restrict__ cursors, int* __restrict__ tile_expert,
                            int* __restrict__ tile_rowstart, int* __restrict__ total_tiles) {
  if (threadIdx.x != 0 || blockIdx.x != 0) return;
  int off = 0, tt = 0;
  for (int e = 0; e < NE; ++e) {
    offsets[e] = off;
    cursors[e] = off;
    int n = counts[e];
    int nt = (n + 127) >> 7;
    for (int i = 0; i < nt; ++i) {
      tile_expert[tt] = e;
      tile_rowstart[tt] = off + i * 128;
      ++tt;
    }
    off += n;
  }
  offsets[NE] = off;   // == NP
  *total_tiles = tt;
}

__global__ void scatter_kernel(const int* __restrict__ topk_e, const float* __restrict__ topk_w,
                               int* __restrict__ cursors, int* __restrict__ row_token,
                               float* __restrict__ row_w) {
  __shared__ int lcnt[NE];
  __shared__ int lbase[NE];
  int tid = threadIdx.x;
  if (tid < NE) lcnt[tid] = 0;
  __syncthreads();
  int t = blockIdx.x * 256 + tid;
  int e = topk_e[t];
  int my = atomicAdd(&lcnt[e], 1);
  __syncthreads();
  if (tid < NE) lbase[tid] = atomicAdd(&cursors[tid], lcnt[tid]);
  __syncthreads();
  row_token[lbase[e] + my] = t / TK;
  row_w[lbase[e] + my] = topk_w[t];
}

// ---------------- GEMM1: H = silu(Xg @ W1_e^T), bf16 out ----------------
// grid: (MAX_TILES, FC/128). Tile 128 rows x 128 F-cols, K = HD.
// LDS rows padded to 40 ushorts (80 B): keeps 16B alignment for ds_read_b128
// and gives all-even distinct bank starts (2-way max, free per m136).

__global__ __launch_bounds__(256) void gemm1_kernel(
    const float* __restrict__ x, const float* __restrict__ w1,
    const int* __restrict__ row_token, const int* __restrict__ offsets,
    const int* __restrict__ tile_expert, const int* __restrict__ tile_rowstart,
    const int* __restrict__ total_tiles,
    unsigned short* __restrict__ Hbuf, int fchunk, int FC) {
  int rt = blockIdx.x;
  if (rt >= *total_tiles) return;
  int e = tile_expert[rt];
  int rstart = tile_rowstart[rt];
  int nvalid = offsets[e + 1] - rstart;
  if (nvalid > 128) nvalid = 128;

  __shared__ unsigned short Asm[128][40];
  __shared__ unsigned short Bsm[128][40];

  int tid = threadIdx.x;
  int fbase = fchunk + blockIdx.y * 128;

  const float* arow[4];
  const float* brow[4];
#pragma unroll
  for (int p = 0; p < 4; ++p) {
    int r = (tid >> 3) + p * 32;
    int rg = rstart + r;
    if (rg > NP - 1) rg = NP - 1;                 // tail tile clamp
    arow[p] = x + (size_t)row_token[rg] * HD;
    brow[p] = w1 + ((size_t)e * FD + (fbase + r)) * HD;
  }
  int c4 = (tid & 7) * 4;

  f32x4 acc[4][4];
  f32x4 vzero = {0.f, 0.f, 0.f, 0.f};
#pragma unroll
  for (int i = 0; i < 4; ++i)
#pragma unroll
    for (int j = 0; j < 4; ++j) acc[i][j] = vzero;

  int lane = tid & 63;
  int wv = tid >> 6;
  int wm = (wv & 1) * 64, wn = (wv >> 1) * 64;
  int lr = lane & 15, lk = (lane >> 4) * 8;

  for (int kb = 0; kb < HD / 32; ++kb) {
    __syncthreads();
    int kc = kb * 32 + c4;
#pragma unroll
    for (int p = 0; p < 4; ++p) {
      int r = (tid >> 3) + p * 32;
      float4 va = *(const float4*)(arow[p] + kc);
      float4 vb = *(const float4*)(brow[p] + kc);
      ushort4 ua; ua.x = f2bf(va.x); ua.y = f2bf(va.y); ua.z = f2bf(va.z); ua.w = f2bf(va.w);
      ushort4 ub; ub.x = f2bf(vb.x); ub.y = f2bf(vb.y); ub.z = f2bf(vb.z); ub.w = f2bf(vb.w);
      *(ushort4*)&Asm[r][c4] = ua;
      *(ushort4*)&Bsm[r][c4] = ub;
    }
    __syncthreads();
    bf16x8 af[4], bfr[4];
#pragma unroll
    for (int i = 0; i < 4; ++i) af[i] = frag_ld(&Asm[wm + i * 16 + lr][lk]);
#pragma unroll
    for (int j = 0; j < 4; ++j) bfr[j] = frag_ld(&Bsm[wn + j * 16 + lr][lk]);
#pragma unroll
    for (int i = 0; i < 4; ++i)
#pragma unroll
      for (int j = 0; j < 4; ++j)
        acc[i][j] = __builtin_amdgcn_mfma_f32_16x16x32_bf16(af[i], bfr[j], acc[i][j], 0, 0, 0);
  }

  int cloc0 = blockIdx.y * 128;
  int rq = (lane >> 4) * 4;
#pragma unroll
  for (int i = 0; i < 4; ++i) {
#pragma unroll
    for (int r = 0; r < 4; ++r) {
      int row = wm + i * 16 + rq + r;
      if (row < nvalid) {
        size_t base = (size_t)(rstart + row) * FC;
#pragma unroll
        for (int j = 0; j < 4; ++j) {
          float v = acc[i][j][r];
          float sv = v / (1.f + __expf(-v));   // silu
          Hbuf[base + (cloc0 + wn + j * 16 + (lane & 15))] = f2bf(sv);
        }
      }
    }
  }
}

// ---------------- GEMM2: Y += diag(w) * (H @ W2_e^T), atomic scatter ----------------
// grid: (MAX_TILES, HD/128). Tile 128 rows x 128 h-cols, K = FC (chunk of F).

__global__ __launch_bounds__(256) void gemm2_kernel(
    const unsigned short* __restrict__ Hbuf, const float* __restrict__ w2,
    const int* __restrict__ row_token, const float* __restrict__ row_w,
    const int* __restrict__ offsets,
    const int* __restrict__ tile_expert, const int* __restrict__ tile_rowstart,
    const int* __restrict__ total_tiles,
    float* __restrict__ y, int fchunk, int FC) {
  int rt = blockIdx.x;
  if (rt >= *total_tiles) return;
  int e = tile_expert[rt];
  int rstart = tile_rowstart[rt];
  int nvalid = offsets[e + 1] - rstart;
  if (nvalid > 128) nvalid = 128;

  __shared__ unsigned short Asm[128][40];
  __shared__ unsigned short Bsm[128][40];

  int tid = threadIdx.x;
  int hbase = blockIdx.y * 128;

  const unsigned short* ahrow[2];
#pragma unroll
  for (int p = 0; p < 2; ++p) {
    int r = (tid >> 2) + p * 64;
    int rg = rstart + r;
    if (rg > NP - 1) rg = NP - 1;
    ahrow[p] = Hbuf + (size_t)rg * FC;
  }
  const float* brow[4];
#pragma unroll
  for (int p = 0; p < 4; ++p) {
    int h = hbase + (tid >> 3) + p * 32;
    brow[p] = w2 + ((size_t)e * HD + h) * FD + fchunk;
  }
  int c8 = (tid & 3) * 8;
  int c4 = (tid & 7) * 4;

  f32x4 acc[4][4];
  f32x4 vzero = {0.f, 0.f, 0.f, 0.f};
#pragma unroll
  for (int i = 0; i < 4; ++i)
#pragma unroll
    for (int j = 0; j < 4; ++j) acc[i][j] = vzero;

  int lane = tid & 63;
  int wv = tid >> 6;
  int wm = (wv & 1) * 64, wn = (wv >> 1) * 64;
  int lr = lane & 15, lk = (lane >> 4) * 8;

  for (int kb = 0; kb < FC / 32; ++kb) {
    __syncthreads();
#pragma unroll
    for (int p = 0; p < 2; ++p) {
      int r = (tid >> 2) + p * 64;
      *(us8*)&Asm[r][c8] = *(const us8*)(ahrow[p] + kb * 32 + c8);  // bf16 direct, 16B
    }
#pragma unroll
    for (int p = 0; p < 4; ++p) {
      int r = (tid >> 3) + p * 32;
      float4 vb = *(const float4*)(brow[p] + kb * 32 + c4);
      ushort4 ub; ub.x = f2bf(vb.x); ub.y = f2bf(vb.y); ub.z = f2bf(vb.z); ub.w = f2bf(vb.w);
      *(ushort4*)&Bsm[r][c4] = ub;
    }
    __syncthreads();
    bf16x8 af[4], bfr[4];
#pragma unroll
    for (int i = 0; i < 4; ++i) af[i] = frag_ld(&Asm[wm + i * 16 + lr][lk]);
#pragma unroll
    for (int j = 0; j < 4; ++j) bfr[j] = frag_ld(&Bsm[wn + j * 16 + lr][lk]);
#pragma unroll
    for (int i = 0; i < 4; ++i)
#pragma unroll
      for (int j = 0; j < 4; ++j)
        acc[i][j] = __builtin_amdgcn_mfma_f32_16x16x32_bf16(af[i], bfr[j], acc[i][j], 0, 0, 0);
  }

  int rq = (lane >> 4) * 4;
#pragma unroll
  for (int i = 0; i < 4; ++i) {
#pragma unroll
    for (int r = 0; r < 4; ++r) {
      int row = wm + i * 16 + rq + r;
      if (row < nvalid) {
        int rg = rstart + row;
        float wgt = row_w[rg];
        float* yrow = y + (size_t)row_token[rg] * HD + hbase;
#pragma unroll
        for (int j = 0; j < 4; ++j)
          atomicAdd(yrow + (wn + j * 16 + (lane & 15)), wgt * acc[i][j][r]);
      }
    }
  }
}

// ---------------- host ----------------

extern "C" void kernel_launch(void* const* d_in, const int* in_sizes, int n_in,
                              void* d_out, int out_size, void* d_ws, size_t ws_size,
                              hipStream_t stream) {
  const float* x      = (const float*)d_in[0];
  const int*   topk_e = (const int*)d_in[1];
  const float* topk_w = (const float*)d_in[2];
  const float* w1     = (const float*)d_in[3];
  const float* w2     = (const float*)d_in[4];
  float* y = (float*)d_out;

  char* ws = (char*)d_ws;
  int* counts        = (int*)(ws + 0);
  int* cursors       = (int*)(ws + 64);
  int* offsets       = (int*)(ws + 128);
  int* total_tiles   = (int*)(ws + 192);
  int* tile_expert   = (int*)(ws + 256);
  int* tile_rowstart = (int*)(ws + 1024);
  int* row_token     = (int*)(ws + 4096);
  float* row_w       = (float*)(ws + 4096 + (size_t)NP * 4);
  unsigned short* Hbuf = (unsigned short*)(ws + 4096 + (size_t)NP * 8);

  // Pick the largest F-chunk whose bf16 H buffer fits the workspace.
  size_t hdr = 4096 + (size_t)NP * 8;
  size_t avail = ws_size > hdr ? ws_size - hdr : 0;
  int FC = FD;
  while (FC > 128 && (size_t)NP * FC * 2 > avail) FC >>= 1;

  hipMemsetAsync(d_out, 0, (size_t)SS * HD * sizeof(float), stream);
  hipMemsetAsync(d_ws, 0, 2048, stream);

  count_kernel<<<NP / 256, 256, 0, stream>>>(topk_e, counts);
  plan_kernel<<<1, 1, 0, stream>>>(counts, offsets, cursors, tile_expert, tile_rowstart, total_tiles);
  scatter_kernel<<<NP / 256, 256, 0, stream>>>(topk_e, topk_w, cursors, row_token, row_w);

  int nchunks = FD / FC;
  for (int c = 0; c < nchunks; ++c) {
    gemm1_kernel<<<dim3(MAX_TILES, FC / 128), 256, 0, stream>>>(
        x, w1, row_token, offsets, tile_expert, tile_rowstart, total_tiles, Hbuf, c * FC, FC);
    gemm2_kernel<<<dim3(MAX_TILES, HD / 128), 256, 0, stream>>>(
        Hbuf, w2, row_token, row_w, offsets, tile_expert, tile_rowstart, total_tiles, y, c * FC, FC);
  }
}